// Round 3
// baseline (309.259 us; speedup 1.0000x reference)
//
#include <hip/hip_runtime.h>
#include <math.h>

#define NF 128
#define HD 8
#define NPG 2000          // nodes per graph
#define PPARTS 4          // aggregation blocks per graph
#define TBL (HD * NPG)    // 16000 floats per agg table
#define SLOPE 0.01f

__device__ __forceinline__ float lrelu(float v) {
    return v > 0.0f ? v : SLOPE * v;
}

// ---------------------------------------------------------------------------
// K1: t1 = x @ W1a  (N x 128)@(128 x 8), coalesced via LDS staging.
// ---------------------------------------------------------------------------
__global__ __launch_bounds__(256) void k_feat(const float* __restrict__ x,
                                              const float* __restrict__ W1a,
                                              float* __restrict__ t1, int N) {
    __shared__ float tile[64 * 132];   // 33 KiB
    __shared__ float wl[NF * HD];      // 4 KiB

    const int t = threadIdx.x;
    const size_t base = (size_t)blockIdx.x * 64;

    ((float4*)wl)[t] = ((const float4*)W1a)[t];

    const float4* xg = (const float4*)(x + base * NF);
#pragma unroll
    for (int i = 0; i < 8; ++i) {
        int f4 = t + i * 256;
        float4 v = xg[f4];
        int flat = f4 * 4;
        int n = flat >> 7;
        int k = flat & 127;
        *(float4*)(tile + n * 132 + k) = v;
    }
    __syncthreads();

    const int n = t >> 2;
    const int c0 = (t & 3) * 2;
    float acc0 = 0.0f, acc1 = 0.0f;
    const float* row = tile + n * 132;
#pragma unroll
    for (int k4 = 0; k4 < 32; ++k4) {
        float4 r = *(const float4*)(row + k4 * 4);
        int kb = k4 * 4 * HD;
        acc0 += r.x * wl[kb + c0];          acc1 += r.x * wl[kb + c0 + 1];
        acc0 += r.y * wl[kb + HD + c0];     acc1 += r.y * wl[kb + HD + c0 + 1];
        acc0 += r.z * wl[kb + 2*HD + c0];   acc1 += r.z * wl[kb + 2*HD + c0 + 1];
        acc0 += r.w * wl[kb + 3*HD + c0];   acc1 += r.w * wl[kb + 3*HD + c0 + 1];
    }
    *(float2*)(t1 + (base + n) * HD + c0) = make_float2(acc0, acc1);
}

// ---------------------------------------------------------------------------
// K2/K4: edge-parallel partial aggregation. 4 blocks per graph, each with its
// own 2000x8 LDS table in PLANE layout agg[c*2000 + n]: bank = (16c + n) % 32
// -> per-channel banks are a bijection of dst%32 (no swizzle math needed).
// Native ds_add_f32 via unsafeAtomicAdd (no return -> no latency chain).
// ---------------------------------------------------------------------------
__global__ __launch_bounds__(1024) void k_aggp(
    const float* __restrict__ feat,      // [N][8] (t1 or u)
    const int* __restrict__ ei,
    float* __restrict__ partials,        // [B*PPARTS][TBL]
    int E, int EPG)
{
    __shared__ __align__(16) float agg[TBL];   // 62.5 KiB

    const int blk = blockIdx.x;
    const int g = blk >> 2;
    const int p = blk & 3;
    const int tid = threadIdx.x;
    const int nodeBase = g * NPG;
    const int epp = EPG / PPARTS;              // 8000
    const int e0 = g * EPG + p * epp;

    float4* a4 = (float4*)agg;
    for (int i = tid; i < TBL / 4; i += 1024)
        a4[i] = make_float4(0.f, 0.f, 0.f, 0.f);
    __syncthreads();

    for (int e = e0 + tid; e < e0 + epp; e += 1024) {
        int src = ei[e];
        int dl = ei[E + e] - nodeBase;
        const float* r = feat + (size_t)src * HD;
        float4 a = *(const float4*)r;
        float4 b = *(const float4*)(r + 4);
        unsafeAtomicAdd(&agg[0 * NPG + dl], a.x);
        unsafeAtomicAdd(&agg[1 * NPG + dl], a.y);
        unsafeAtomicAdd(&agg[2 * NPG + dl], a.z);
        unsafeAtomicAdd(&agg[3 * NPG + dl], a.w);
        unsafeAtomicAdd(&agg[4 * NPG + dl], b.x);
        unsafeAtomicAdd(&agg[5 * NPG + dl], b.y);
        unsafeAtomicAdd(&agg[6 * NPG + dl], b.z);
        unsafeAtomicAdd(&agg[7 * NPG + dl], b.w);
    }
    __syncthreads();

    // coalesced spill of the raw table
    float4* dst = (float4*)(partials + (size_t)blk * TBL);
    for (int i = tid; i < TBL / 4; i += 1024) dst[i] = a4[i];
}

// ---------------------------------------------------------------------------
// K3: combine 4 partials + MLP1 + u = h @ W2a. Node-parallel, 512 blocks.
// ---------------------------------------------------------------------------
__global__ __launch_bounds__(256) void k_node1(
    const float* __restrict__ t1, const float* __restrict__ partials,
    float* __restrict__ u,
    const float* __restrict__ b1a, const float* __restrict__ W1b,
    const float* __restrict__ b1b, const float* __restrict__ W2a)
{
    const int g = blockIdx.x >> 3;
    const int nl = (blockIdx.x & 7) * 250 + threadIdx.x;
    if (threadIdx.x >= 250) return;
    const int n = g * NPG + nl;
    const float* pg = partials + (size_t)g * PPARTS * TBL;

    float a[HD];
#pragma unroll
    for (int c = 0; c < HD; ++c) {
        float s = 0.f;
#pragma unroll
        for (int p = 0; p < PPARTS; ++p)
            s += pg[(size_t)p * TBL + c * NPG + nl];   // coalesced per (p,c)
        a[c] = s;
    }
    const float* ti = t1 + (size_t)n * HD;
    float z[HD];
#pragma unroll
    for (int c = 0; c < HD; ++c) z[c] = lrelu(ti[c] + a[c] + b1a[c]);

    float h[HD];
#pragma unroll
    for (int j = 0; j < HD; ++j) {
        float acc = b1b[j];
#pragma unroll
        for (int c = 0; c < HD; ++c) acc += z[c] * W1b[c * HD + j];
        h[j] = lrelu(acc);
    }
    float uu[HD];
#pragma unroll
    for (int j = 0; j < HD; ++j) {
        float acc = 0.0f;
#pragma unroll
        for (int c = 0; c < HD; ++c) acc += h[c] * W2a[c * HD + j];
        uu[j] = acc;
    }
    float* ur = u + (size_t)n * HD;
    *(float4*)ur       = make_float4(uu[0], uu[1], uu[2], uu[3]);
    *(float4*)(ur + 4) = make_float4(uu[4], uu[5], uu[6], uu[7]);
}

// ---------------------------------------------------------------------------
// K5: combine layer-2 partials + MLP2 + FC1 + per-block FC2 partial sums.
// Node-parallel, 512 blocks; partial sums -> gpart[g][8][2].
// ---------------------------------------------------------------------------
__global__ __launch_bounds__(256) void k_node2(
    const float* __restrict__ u, const float* __restrict__ partials,
    const float* __restrict__ b2a, const float* __restrict__ W2b,
    const float* __restrict__ b2b, const float* __restrict__ Wf1,
    const float* __restrict__ bf1, const float* __restrict__ Wf2,
    float* __restrict__ gpart)
{
    __shared__ float red[8];
    const int g = blockIdx.x >> 3;
    const int sb = blockIdx.x & 7;
    const int tid = threadIdx.x;
    const int nl = sb * 250 + tid;
    const bool act = (tid < 250);

    float acc0 = 0.f, acc1 = 0.f;
    if (act) {
        const float* pg = partials + (size_t)g * PPARTS * TBL;
        float a[HD];
#pragma unroll
        for (int c = 0; c < HD; ++c) {
            float s = 0.f;
#pragma unroll
            for (int p = 0; p < PPARTS; ++p)
                s += pg[(size_t)p * TBL + c * NPG + nl];
            a[c] = s;
        }
        const float* ui = u + (size_t)(g * NPG + nl) * HD;
        float z[HD];
#pragma unroll
        for (int c = 0; c < HD; ++c) z[c] = lrelu(ui[c] + a[c] + b2a[c]);

        float sv = bf1[0];
#pragma unroll
        for (int j = 0; j < HD; ++j) {
            float acc = b2b[j];
#pragma unroll
            for (int c = 0; c < HD; ++c) acc += z[c] * W2b[c * HD + j];
            sv += lrelu(acc) * Wf1[j];
        }
        float pfeat = lrelu(sv);
        acc0 = pfeat * Wf2[nl * 2 + 0];
        acc1 = pfeat * Wf2[nl * 2 + 1];
    }

#pragma unroll
    for (int off = 32; off > 0; off >>= 1) {
        acc0 += __shfl_down(acc0, off);
        acc1 += __shfl_down(acc1, off);
    }
    int wave = tid >> 6;
    if ((tid & 63) == 0) { red[wave * 2] = acc0; red[wave * 2 + 1] = acc1; }
    __syncthreads();
    if (tid == 0) {
        float s0 = red[0] + red[2] + red[4] + red[6];
        float s1 = red[1] + red[3] + red[5] + red[7];
        gpart[(g * 8 + sb) * 2 + 0] = s0;
        gpart[(g * 8 + sb) * 2 + 1] = s1;
    }
}

// ---------------------------------------------------------------------------
// K6: finalize — sum 8 block partials per graph, bias, log_softmax.
// ---------------------------------------------------------------------------
__global__ __launch_bounds__(64) void k_fin(const float* __restrict__ gpart,
                                            const float* __restrict__ bf2,
                                            float* __restrict__ out, int Bn) {
    int g = threadIdx.x;
    if (g >= Bn) return;
    float y0 = bf2[0], y1 = bf2[1];
#pragma unroll
    for (int b = 0; b < 8; ++b) {
        y0 += gpart[(g * 8 + b) * 2 + 0];
        y1 += gpart[(g * 8 + b) * 2 + 1];
    }
    float m = fmaxf(y0, y1);
    float lse = m + logf(expf(y0 - m) + expf(y1 - m));
    out[g * 2 + 0] = y0 - lse;
    out[g * 2 + 1] = y1 - lse;
}

// ---------------------------------------------------------------------------
extern "C" void kernel_launch(void* const* d_in, const int* in_sizes, int n_in,
                              void* d_out, int out_size, void* d_ws, size_t ws_size,
                              hipStream_t stream) {
    const float* x   = (const float*)d_in[0];
    const int*   ei  = (const int*)  d_in[1];
    const float* W1a = (const float*)d_in[3];
    const float* b1a = (const float*)d_in[4];
    const float* W1b = (const float*)d_in[5];
    const float* b1b = (const float*)d_in[6];
    const float* W2a = (const float*)d_in[7];
    const float* b2a = (const float*)d_in[8];
    const float* W2b = (const float*)d_in[9];
    const float* b2b = (const float*)d_in[10];
    const float* Wf1 = (const float*)d_in[11];
    const float* bf1 = (const float*)d_in[12];
    const float* Wf2 = (const float*)d_in[13];
    const float* bf2 = (const float*)d_in[14];

    int N   = in_sizes[0] / NF;        // 128000
    int E   = in_sizes[1] / 2;         // 2048000
    int Bn  = N / NPG;                 // 64 graphs
    int EPG = E / Bn;                  // 32000

    // workspace carve-up
    float* t1    = (float*)d_ws;                       // N*8       (4.1 MB)
    float* u     = t1 + (size_t)N * HD;                // N*8       (4.1 MB)
    float* parts = u + (size_t)N * HD;                 // Bn*4*TBL  (16.4 MB)
    float* gpart = parts + (size_t)Bn * PPARTS * TBL;  // Bn*8*2

    k_feat <<<N / 64, 256, 0, stream>>>(x, W1a, t1, N);
    k_aggp <<<Bn * PPARTS, 1024, 0, stream>>>(t1, ei, parts, E, EPG);
    k_node1<<<Bn * 8, 256, 0, stream>>>(t1, parts, u, b1a, W1b, b1b, W2a);
    k_aggp <<<Bn * PPARTS, 1024, 0, stream>>>(u, ei, parts, E, EPG);
    k_node2<<<Bn * 8, 256, 0, stream>>>(u, parts, b2a, W2b, b2b, Wf1, bf1,
                                        Wf2, gpart);
    k_fin  <<<1, 64, 0, stream>>>(gpart, bf2, (float*)d_out, Bn);
}